// Round 13
// baseline (249.110 us; speedup 1.0000x reference)
//
#include <hip/hip_runtime.h>

// ProposalLayer for Faster R-CNN RPN on MI355X — 2 kernels, hybrid placement.
// B=4, H=64, W=96, A=9 anchors, N=55296/image. TEST: pre=6000, post=300.
//
// kA_decode (864x256, FULL CHIP — streaming phase): decode boxes+keys +
//   global 15-bit score histogram.
// kB_sortnms (4x1024, one block per image — serial per-image phases):
//   pivot from histogram (SCALAR-ONLY walks; no per-thread arrays -> no
//   scratch spill, round-12 fix) -> counting-scatter into packed bucket
//   segments in LDS -> per-bucket register bitonic (<=256, round-9 proven)
//   -> dedicated box-gather to g_sbox (round-10 fix) -> 16-wave batched
//   greedy NMS with contiguous staging (round-6 proven) -> hist reset.
// Cross-call invariants: g_h15 zeroed by kB at end (first call sees .bss 0).

#define NB 4
#define AH 64
#define AW 96
#define NA 9
#define NPOS (AH*AW)        // 6144
#define NPC (NPOS*NA)       // 55296
#define LDSN 8192           // candidate capacity (u64) = 64KB
#define HBITS 15
#define HSZ (1<<HBITS)      // 32768
#define HSH (32-HBITS)      // 17
#define NTHR 1024
#define WIN 2048            // bucket window (top keys span ~140 bins; big margin)
#define DYN_LDS (65536 + 50560)

typedef unsigned long long u64;
typedef unsigned int u32;

// anchors from _generate_anchors(16,(0.5,1,2),(8,16,32)) — verified vs numpy
__constant__ float c_anchors[NA][4] = {
  { -84.f,  -40.f,  99.f,  55.f},
  {-176.f,  -88.f, 191.f, 103.f},
  {-360.f, -184.f, 375.f, 199.f},
  { -56.f,  -56.f,  71.f,  71.f},
  {-120.f, -120.f, 135.f, 135.f},
  {-248.f, -248.f, 263.f, 263.f},
  { -36.f,  -80.f,  51.f,  95.f},
  { -80.f, -168.f,  95.f, 183.f},
  {-168.f, -344.f, 183.f, 359.f},
};

__device__ u32    g_keys[NB][NPC];   // storage order i2 = a*NPOS+pos
__device__ float4 g_boxes[NB][NPC];
__device__ u32    g_h15[NB][HSZ];
__device__ float4 g_sbox[NB][LDSN];  // boxes in exact sorted order

// exact-equivalent "iou > 0.7f": margin-guarded multiply compare with exact
// IEEE-division fallback on the ~never-taken borderline.
__device__ __forceinline__ bool iou_gt(float4 a, float areaA, float4 q, float areaQ) {
#pragma clang fp contract(off)
  float iw = fminf(a.z, q.z) - fmaxf(a.x, q.x) + 1.0f; iw = fmaxf(iw, 0.0f);
  float ih = fminf(a.w, q.w) - fmaxf(a.y, q.y) + 1.0f; ih = fmaxf(ih, 0.0f);
  float inter = iw * ih;
  float denom = areaA + areaQ - inter;
  float d = inter - 0.7f * denom;
  if (__builtin_expect(fabsf(d) <= 4e-6f * denom, 0))
    return (inter / denom) > 0.7f;
  return d > 0.0f;
}

// ================= kA: decode (full chip) =================
__global__ void __launch_bounds__(256)
kA_decode(const float* __restrict__ cls, const float* __restrict__ dlt,
          const float* __restrict__ ish) {
#pragma clang fp contract(off)
  const int UPB = NPOS/256;                  // 24
  int bid = blockIdx.x;
  int b   = bid / (NA*UPB);
  int r   = bid % (NA*UPB);
  int a   = r / UPB;
  int pos = (r % UPB) * 256 + threadIdx.x;
  int i2  = a * NPOS + pos;

  int wx = pos % AW;
  int hy = pos / AW;

  float score = cls[(b * (2*NA) + NA + a) * NPOS + pos];
  const float* dp = dlt + (b * (4*NA) + a*4) * NPOS + pos;
  float d0 = dp[0];
  float d1 = dp[NPOS];
  float d2 = dp[2*NPOS];
  float d3 = dp[3*NPOS];

  float shx = (float)(wx * 16);
  float shy = (float)(hy * 16);
  float ax1 = c_anchors[a][0] + shx;
  float ay1 = c_anchors[a][1] + shy;
  float ax2 = c_anchors[a][2] + shx;
  float ay2 = c_anchors[a][3] + shy;

  float aw_ = ax2 - ax1 + 1.0f;
  float ah_ = ay2 - ay1 + 1.0f;
  float acx = ax1 + 0.5f * aw_;
  float acy = ay1 + 0.5f * ah_;

  float pcx = d0 * aw_ + acx;
  float pcy = d1 * ah_ + acy;
  float pw  = expf(d2) * aw_;
  float ph  = expf(d3) * ah_;

  float x1 = pcx - 0.5f * pw;
  float y1 = pcy - 0.5f * ph;
  float x2 = pcx + 0.5f * pw;
  float y2 = pcy + 0.5f * ph;

  float imh = ish[b*2 + 0];
  float imw = ish[b*2 + 1];
  x1 = fminf(fmaxf(x1, 0.0f), imw - 1.0f);
  x2 = fminf(fmaxf(x2, 0.0f), imw - 1.0f);
  y1 = fminf(fmaxf(y1, 0.0f), imh - 1.0f);
  y2 = fminf(fmaxf(y2, 0.0f), imh - 1.0f);

  bool valid = ((x2 - x1 + 1.0f) >= 16.0f) && ((y2 - y1 + 1.0f) >= 16.0f);

  g_boxes[b][i2] = make_float4(x1, y1, x2, y2);

  u32 key = 0u;
  if (valid) {
    u32 ub = __float_as_uint(score);
    key = (ub >> 31) ? ~ub : (ub | 0x80000000u);  // monotonic flip
  }
  g_keys[b][i2] = key;
  atomicAdd(&g_h15[b][key >> HSH], 1u);           // key==0 -> bucket 0
}

// ================= kB: pivot + counting-sort + gather + NMS =================
__global__ void __launch_bounds__(NTHR)
kB_sortnms(float* __restrict__ out, const int* __restrict__ train, int post) {
#pragma clang fp contract(off)
  const int tid = threadIdx.x;
  const int b   = blockIdx.x;
  const int pre = train[0] ? 12000 : 6000;
  const int lane = tid & 63;
  const int wid  = tid >> 6;   // 16 waves

  extern __shared__ __align__(16) unsigned char smem[];
  u64* sl = (u64*)smem;                               // [LDSN] 64KB
  unsigned char* r2 = smem + 65536;                   // 50560B region
  u32* base = (u32*)r2;                               // [WIN] (phases A-C)
  u32* cntw = base + WIN;                             // [WIN]

  __shared__ u32 csum[NTHR];
  __shared__ u32 c32[32];
  __shared__ u32 c32s[33];
  __shared__ int sBest;
  __shared__ u32 sC;
  __shared__ int s_nk;

  // ---------- phase A: pivot + window bases (scalar-only; 3 streaming
  // passes over this thread's 32 bins — NO per-thread array, no spill) ----
  const int CH = HSZ / NTHR;   // 32 bins/thread
  const u32* __restrict__ hrow = &g_h15[b][tid * CH];
  {
    u32 s = 0;
    const uint4* hp = (const uint4*)hrow;
#pragma unroll
    for (int q = 0; q < CH/4; ++q) { uint4 v = hp[q]; s += v.x + v.y + v.z + v.w; }
    csum[tid] = s;
    if (tid == 0) { sBest = 0; sC = 0u; s_nk = 0; }
  }
  __syncthreads();
  if (tid < 32) {
    u32 ss = 0;
    for (int q = 0; q < 32; ++q) ss += csum[tid*32 + q];
    c32[tid] = ss;
  }
  __syncthreads();
  if (tid == 0) {
    u32 run = 0; c32s[32] = 0;
    for (int c = 31; c >= 0; --c) { run += c32[c]; c32s[c] = run; }
  }
  __syncthreads();
  u32 runSave;
  {
    // pass 2: find pivot (re-read bins from L2)
    u32 run = c32s[(tid >> 5) + 1];
    for (int t2 = (tid | 31); t2 > tid; --t2) run += csum[t2];
    runSave = run;
    int loc = 0;
#pragma unroll
    for (int q = CH-1; q >= 0; --q) {
      run += hrow[q];
      if (!loc && run >= (u32)pre) {
        int T = tid * CH + q;
        if (T >= 1) loc = T;
      }
    }
    if (loc) atomicMax(&sBest, loc);
  }
  __syncthreads();
  const int P = sBest;                          // window start
  const u32 pivot = P ? ((u32)P << HSH) : 1u;
  {
    // pass 3: window base offsets (=suffix above bin) + C (re-read bins)
    u32 run = runSave;
    u32 partC = 0;
#pragma unroll
    for (int q = CH-1; q >= 0; --q) {
      u32 h = hrow[q];
      int T = tid * CH + q;
      int w = T - P;
      if (w >= 0 && w < WIN) base[w] = run;     // count of keys in bins > T
      if (T >= P) partC += h;
      run += h;
    }
    if (partC) atomicAdd(&sC, partC);
    for (int w = tid; w < WIN; w += NTHR) cntw[w] = 0u;
  }
  __syncthreads();
  int C = (int)sC; if (C > LDSN) C = LDSN;
  const int Kb = min(pre, C);

  // ---------- phase B: counting-scatter into packed bucket segments ----------
  for (int i2 = tid; i2 < NPC; i2 += NTHR) {
    u32 key = g_keys[b][i2];
    if (key >= pivot) {
      int w = (int)(key >> HSH) - P;
      if (w < 0) w = 0; if (w > WIN-1) w = WIN-1;
      int slot = (int)base[w] + (int)atomicAdd(&cntw[w], 1u);
      if (slot < LDSN) {
        int a = i2 / NPOS, pos = i2 - a * NPOS;
        u32 iref = (u32)(pos * NA + a);          // reference flat order
        sl[slot] = ((u64)key << 32) | (u64)(0xFFFFFFFFu - iref);
      }
    }
  }
  __syncthreads();

  // ---------- phase C: per-bucket register bitonic (<=256, desc) ----------
  for (int w = wid; w < WIN; w += 16) {
    int cw = (int)cntw[w];
    if (cw < 2) continue;
    if (cw > 256) cw = 256;                      // impossible-case clamp
    int bse = (int)base[w];
    u64 v[4];
#pragma unroll
    for (int s = 0; s < 4; ++s) {
      int idx = s*64 + lane;
      v[s] = (idx < cw) ? sl[bse + idx] : 0ull;  // pads (0) sort to the end
    }
    for (int k = 2; k <= 256; k <<= 1) {
      for (int j = k >> 1; j; j >>= 1) {
        if (j >= 64) {
          int js = j >> 6;                        // 1 or 2
#pragma unroll
          for (int sa = 0; sa < 4; ++sa) {
            int sb = sa ^ js;
            if (sb > sa) {
              int idx = sa*64 + lane;
              bool dir = ((idx & k) == 0);
              u64 A = v[sa], B = v[sb];
              if ((A < B) == dir) { v[sa] = B; v[sb] = A; }
            }
          }
        } else {
#pragma unroll
          for (int s = 0; s < 4; ++s) {
            u64 o = __shfl_xor(v[s], j);
            int idx = s*64 + lane;
            bool dir   = ((idx & k) == 0);
            bool lower = ((lane & j) == 0);
            v[s] = ((v[s] > o) == (lower == dir)) ? v[s] : o;
          }
        }
      }
    }
#pragma unroll
    for (int s = 0; s < 4; ++s) {
      int idx = s*64 + lane;
      if (idx < cw) sl[bse + idx] = v[s];
    }
  }
  __syncthreads();

  // ---------- phase C2: dedicated box-gather to g_sbox (high MLP) ----------
  for (int r = tid; r < Kb; r += NTHR) {
    u32 iref = 0xFFFFFFFFu - (u32)(sl[r] & 0xFFFFFFFFull);
    int pos = iref / NA, a = iref - pos * NA;
    g_sbox[b][r] = g_boxes[b][a * NPOS + pos];
  }
  __syncthreads();   // sl/base/cntw dead; r2 free for NMS

  // ---------- phase D: 16-wave batched greedy NMS (round-6 proven) ----------
  {
    float4* kbox = (float4*)r2;                          // [2048] 32KB
    float*  kar  = (float*)(r2 + 32768);                 // [2048]
    float4* cbox = (float4*)(r2 + 40960);                // [64]
    float*  car  = (float*)(r2 + 41984);                 // [64]
    u64 (*conf16)[64] = (u64 (*)[64])(r2 + 42240);       // [16][64]
    u64* sup16 = (u64*)(r2 + 50432);                     // [16]

    // stage chunk 0 (contiguous)
    if (wid == 15) {
      float4 bx0 = (lane < Kb) ? g_sbox[b][lane] : make_float4(0.f,0.f,-1.f,-1.f);
      cbox[lane] = bx0;
      car[lane]  = (bx0.z - bx0.x + 1.0f) * (bx0.w - bx0.y + 1.0f);
    }
    __syncthreads();

    int nk = 0;
    u64 laneBitsBelow = (lane == 0) ? 0ull : (~0ull >> (64 - lane));

    for (int bs = 0; bs < Kb; bs += 64) {
      float4 bx  = cbox[lane];
      float area = car[lane];
      bool active = (bs + lane < Kb);

      // wave15: prefetch next chunk (contiguous; hidden under supp loop)
      float4 nxt = make_float4(0.f, 0.f, -1.f, -1.f);
      if (wid == 15) {
        int c2 = bs + 64 + lane;
        if (c2 < Kb) nxt = g_sbox[b][c2];
      }

      // suppression vs kept boxes: stride-16, unrolled x4
      int supp = active ? 0 : 1;
      {
        int t = wid;
        for (; t + 48 < nk; t += 64) {
          supp |= (int)iou_gt(bx, area, kbox[t],    kar[t]);
          supp |= (int)iou_gt(bx, area, kbox[t+16], kar[t+16]);
          supp |= (int)iou_gt(bx, area, kbox[t+32], kar[t+32]);
          supp |= (int)iou_gt(bx, area, kbox[t+48], kar[t+48]);
        }
        for (; t < nk; t += 16) supp |= (int)iou_gt(bx, area, kbox[t], kar[t]);
      }
      u64 sb = __ballot(supp);
      if (lane == 0) sup16[wid] = sb;

      // intra-chunk conflict bits: wave w covers j in [w*4, w*4+4)
      {
        u64 confp = 0ull;
#pragma unroll
        for (int q = 0; q < 4; ++q) {
          int j = (wid << 2) + q;
          if (iou_gt(bx, area, cbox[j], car[j])) confp |= (1ull << j);
        }
        conf16[wid][lane] = confp;
      }
      __syncthreads();   // sup16/conf16 ready; cbox free to overwrite

      if (wid == 0) {
        u64 conf = 0ull;
#pragma unroll
        for (int w = 0; w < 16; ++w) conf |= conf16[w][lane];
        conf &= laneBitsBelow;
        u64 supAll = 0ull;
#pragma unroll
        for (int w = 0; w < 16; ++w) supAll |= sup16[w];
        u64 pending = ~supAll;
        u64 keptmask = 0ull;
        while (pending) {
          int i = __ffsll(pending) - 1;
          keptmask |= (1ull << i);
          u64 confb = __ballot((int)((conf >> i) & 1ull));
          pending &= ~confb;
          pending &= ~(1ull << i);
        }
        int myPos = nk + __popcll(keptmask & laneBitsBelow);
        if (((keptmask >> lane) & 1ull) && myPos < post) {
          kbox[myPos] = bx;
          kar [myPos] = area;
          float* o = out + ((size_t)b * post + myPos) * 5;
          o[0] = (float)b; o[1] = bx.x; o[2] = bx.y; o[3] = bx.z; o[4] = bx.w;
        }
        if (lane == 0) s_nk = nk + __popcll(keptmask);
      } else if (wid == 15) {
        cbox[lane] = nxt;
        car[lane]  = (nxt.z - nxt.x + 1.0f) * (nxt.w - nxt.y + 1.0f);
      }
      __syncthreads();   // s_nk, kbox, new cbox ready
      nk = s_nk;
      if (nk >= post) break;
    }

    nk = min(nk, post);
    for (int rr = nk + tid; rr < post; rr += NTHR) {
      float* o = out + ((size_t)b * post + rr) * 5;
      o[0] = (float)b; o[1] = 0.0f; o[2] = 0.0f; o[3] = 0.0f; o[4] = 0.0f;
    }
  }

  // ---------- phase E: reset histogram for next call ----------
  {
    uint4* hz = (uint4*)&g_h15[b][0];
    uint4 z = make_uint4(0u,0u,0u,0u);
    for (int q = tid; q < HSZ/4; q += NTHR) hz[q] = z;
  }
}

extern "C" void kernel_launch(void* const* d_in, const int* in_sizes, int n_in,
                              void* d_out, int out_size, void* d_ws, size_t ws_size,
                              hipStream_t stream) {
  (void)in_sizes; (void)n_in; (void)d_ws; (void)ws_size;
  const float* cls   = (const float*)d_in[0];
  const float* dlt   = (const float*)d_in[1];
  const float* ish   = (const float*)d_in[2];
  const int*   train = (const int*)d_in[3];
  float* out = (float*)d_out;

  int post = out_size / (NB * 5);  // 300 for TEST, 2000 for TRAIN

  // allow >64KB dynamic LDS (gfx950: 160KB/CU); host-side, capture-safe
  (void)hipFuncSetAttribute((const void*)kB_sortnms,
      hipFuncAttributeMaxDynamicSharedMemorySize, DYN_LDS);

  kA_decode<<<NB*NA*(NPOS/256), 256, 0, stream>>>(cls, dlt, ish);
  kB_sortnms<<<NB, NTHR, DYN_LDS, stream>>>(out, train, post);
}

// Round 14
// 192.758 us; speedup vs baseline: 1.2923x; 1.2923x over previous
//
#include <hip/hip_runtime.h>

// ProposalLayer for Faster R-CNN RPN on MI355X — 2 kernels, hybrid placement.
// B=4, H=64, W=96, A=9 anchors, N=55296/image. TEST: pre=6000, post=300.
//
// kA_decode (864x256, FULL CHIP): decode boxes+keys + global 15-bit histogram.
// kB_sortnms (4x1024, one block per image):
//   COALESCED hierarchical pivot (round-13 fix: group-sums + LDS suffix
//   scans; no 128B-stride per-lane histogram walks) -> counting-scatter into
//   packed bucket segments in LDS -> per-bucket register bitonic (round-9)
//   -> dedicated box-gather to g_sbox -> 16-wave batched greedy NMS with
//   contiguous staging (round-6 proven) -> hist reset.
// Cross-call invariants: g_h15 zeroed by kB at end (first call sees .bss 0).

#define NB 4
#define AH 64
#define AW 96
#define NA 9
#define NPOS (AH*AW)        // 6144
#define NPC (NPOS*NA)       // 55296
#define LDSN 8192           // candidate capacity (u64) = 64KB
#define HBITS 15
#define HSZ (1<<HBITS)      // 32768
#define HSH (32-HBITS)      // 17
#define NTHR 1024
#define WIN 2048            // bucket window (real span ~70-200 bins; 10x margin)
#define DYN_LDS (65536 + 50560)

typedef unsigned long long u64;
typedef unsigned int u32;

// anchors from _generate_anchors(16,(0.5,1,2),(8,16,32)) — verified vs numpy
__constant__ float c_anchors[NA][4] = {
  { -84.f,  -40.f,  99.f,  55.f},
  {-176.f,  -88.f, 191.f, 103.f},
  {-360.f, -184.f, 375.f, 199.f},
  { -56.f,  -56.f,  71.f,  71.f},
  {-120.f, -120.f, 135.f, 135.f},
  {-248.f, -248.f, 263.f, 263.f},
  { -36.f,  -80.f,  51.f,  95.f},
  { -80.f, -168.f,  95.f, 183.f},
  {-168.f, -344.f, 183.f, 359.f},
};

__device__ u32    g_keys[NB][NPC];   // storage order i2 = a*NPOS+pos
__device__ float4 g_boxes[NB][NPC];
__device__ u32    g_h15[NB][HSZ];
__device__ float4 g_sbox[NB][LDSN];  // boxes in exact sorted order

// exact-equivalent "iou > 0.7f": margin-guarded multiply compare with exact
// IEEE-division fallback on the ~never-taken borderline.
__device__ __forceinline__ bool iou_gt(float4 a, float areaA, float4 q, float areaQ) {
#pragma clang fp contract(off)
  float iw = fminf(a.z, q.z) - fmaxf(a.x, q.x) + 1.0f; iw = fmaxf(iw, 0.0f);
  float ih = fminf(a.w, q.w) - fmaxf(a.y, q.y) + 1.0f; ih = fmaxf(ih, 0.0f);
  float inter = iw * ih;
  float denom = areaA + areaQ - inter;
  float d = inter - 0.7f * denom;
  if (__builtin_expect(fabsf(d) <= 4e-6f * denom, 0))
    return (inter / denom) > 0.7f;
  return d > 0.0f;
}

// ================= kA: decode (full chip) =================
__global__ void __launch_bounds__(256)
kA_decode(const float* __restrict__ cls, const float* __restrict__ dlt,
          const float* __restrict__ ish) {
#pragma clang fp contract(off)
  const int UPB = NPOS/256;                  // 24
  int bid = blockIdx.x;
  int b   = bid / (NA*UPB);
  int r   = bid % (NA*UPB);
  int a   = r / UPB;
  int pos = (r % UPB) * 256 + threadIdx.x;
  int i2  = a * NPOS + pos;

  int wx = pos % AW;
  int hy = pos / AW;

  float score = cls[(b * (2*NA) + NA + a) * NPOS + pos];
  const float* dp = dlt + (b * (4*NA) + a*4) * NPOS + pos;
  float d0 = dp[0];
  float d1 = dp[NPOS];
  float d2 = dp[2*NPOS];
  float d3 = dp[3*NPOS];

  float shx = (float)(wx * 16);
  float shy = (float)(hy * 16);
  float ax1 = c_anchors[a][0] + shx;
  float ay1 = c_anchors[a][1] + shy;
  float ax2 = c_anchors[a][2] + shx;
  float ay2 = c_anchors[a][3] + shy;

  float aw_ = ax2 - ax1 + 1.0f;
  float ah_ = ay2 - ay1 + 1.0f;
  float acx = ax1 + 0.5f * aw_;
  float acy = ay1 + 0.5f * ah_;

  float pcx = d0 * aw_ + acx;
  float pcy = d1 * ah_ + acy;
  float pw  = expf(d2) * aw_;
  float ph  = expf(d3) * ah_;

  float x1 = pcx - 0.5f * pw;
  float y1 = pcy - 0.5f * ph;
  float x2 = pcx + 0.5f * pw;
  float y2 = pcy + 0.5f * ph;

  float imh = ish[b*2 + 0];
  float imw = ish[b*2 + 1];
  x1 = fminf(fmaxf(x1, 0.0f), imw - 1.0f);
  x2 = fminf(fmaxf(x2, 0.0f), imw - 1.0f);
  y1 = fminf(fmaxf(y1, 0.0f), imh - 1.0f);
  y2 = fminf(fmaxf(y2, 0.0f), imh - 1.0f);

  bool valid = ((x2 - x1 + 1.0f) >= 16.0f) && ((y2 - y1 + 1.0f) >= 16.0f);

  g_boxes[b][i2] = make_float4(x1, y1, x2, y2);

  u32 key = 0u;
  if (valid) {
    u32 ub = __float_as_uint(score);
    key = (ub >> 31) ? ~ub : (ub | 0x80000000u);  // monotonic flip
  }
  g_keys[b][i2] = key;
  atomicAdd(&g_h15[b][key >> HSH], 1u);           // key==0 -> bucket 0
}

// ================= kB: pivot + counting-sort + gather + NMS =================
__global__ void __launch_bounds__(NTHR)
kB_sortnms(float* __restrict__ out, const int* __restrict__ train, int post) {
#pragma clang fp contract(off)
  const int tid = threadIdx.x;
  const int b   = blockIdx.x;
  const int pre = train[0] ? 12000 : 6000;
  const int lane = tid & 63;
  const int wid  = tid >> 6;   // 16 waves

  extern __shared__ __align__(16) unsigned char smem[];
  u64* sl = (u64*)smem;                               // [LDSN] 64KB
  unsigned char* r2 = smem + 65536;                   // 50560B region
  u32* base = (u32*)r2;                               // [WIN]
  u32* cntw = base + WIN;                             // [WIN]

  __shared__ u32 gsum[32];
  __shared__ u32 gsuf[33];
  __shared__ int sG;
  __shared__ int sT;
  __shared__ u32 sU0;
  __shared__ int s_nk;

  // ========== phase A: coalesced hierarchical pivot + window bases ==========
  // A1: group sums (32 groups of 1024 bins), coalesced strided reads
  {
    int g = tid >> 5, j = tid & 31;
    const u32* __restrict__ hg = &g_h15[b][g * 1024];
    u32 part = 0;
#pragma unroll
    for (int k = 0; k < 32; ++k) part += hg[k*32 + j];
#pragma unroll
    for (int m = 16; m >= 1; m >>= 1) part += __shfl_xor(part, m);
    if (j == 0) gsum[g] = part;
  }
  if (tid == 0) { sG = -1; sT = -1; s_nk = 0; }
  __syncthreads();
  // A2: group suffix sums
  if (tid == 0) {
    u32 r = 0; gsuf[32] = 0;
    for (int g = 31; g >= 0; --g) { r += gsum[g]; gsuf[g] = r; }
  }
  __syncthreads();
  // A3: pivot group G = max g with gsuf[g] >= pre
  if (tid < 32 && gsuf[tid] >= (u32)pre) atomicMax(&sG, tid);
  __syncthreads();
  const int G  = sG;
  const int Gc = (G < 0) ? 0 : G;
  // A4: within-group (1024 bins) inclusive suffix scan in cntw (coalesced)
  cntw[tid] = g_h15[b][Gc * 1024 + tid];
  __syncthreads();
  for (int d = 1; d < 1024; d <<= 1) {
    u32 add = (tid + d < 1024) ? cntw[tid + d] : 0u;
    __syncthreads();
    cntw[tid] += add;
    __syncthreads();
  }
  // A5: pivot bin t* = max t with gsuf[G+1]+sfx(t) >= pre (and global bin >= 1)
  if (G >= 0) {
    u32 sfx = gsuf[G + 1] + cntw[tid];
    if (sfx >= (u32)pre && (G * 1024 + tid) >= 1) atomicMax(&sT, tid);
  }
  __syncthreads();
  int P; u32 SP;
  if (sT >= 0) { P = G * 1024 + sT; SP = gsuf[G + 1] + cntw[sT]; }
  else         { P = 1; SP = gsuf[0] - g_h15[b][0]; }   // degenerate: all valid
  const u32 pivot = (u32)P << HSH;
  const u32 hP = g_h15[b][P];
  __syncthreads();   // cntw[sT] consumed; cntw free
  // A6: window suffix scan (2048 bins from P+1) in base; then bases
  {
    int i0 = P + 1 + tid, i1 = i0 + 1024;
    base[tid]        = (i0 < HSZ) ? g_h15[b][i0] : 0u;
    base[tid + 1024] = (i1 < HSZ) ? g_h15[b][i1] : 0u;
  }
  __syncthreads();
  for (int d = 1; d < 2048; d <<= 1) {
    u32 a0 = (tid + d < 2048) ? base[tid + d] : 0u;
    u32 a1 = (tid + 1024 + d < 2048) ? base[tid + 1024 + d] : 0u;
    __syncthreads();
    base[tid] += a0;
    base[tid + 1024] += a1;
    __syncthreads();
  }
  if (tid == 0) sU0 = base[0];
  __syncthreads();
  {
    // base[w] := SP - h[P] - (U0 - U[w]) = count of keys in bins > P+w
    u32 adj = SP - hP - sU0;
    base[tid] += adj;
    base[tid + 1024] += adj;
    cntw[tid] = 0u;
    cntw[tid + 1024] = 0u;
  }
  __syncthreads();
  int C = (int)SP; if (C > LDSN) C = LDSN;
  const int Kb = min(pre, C);

  // ---------- phase B: counting-scatter into packed bucket segments ----------
  for (int i2 = tid; i2 < NPC; i2 += NTHR) {
    u32 key = g_keys[b][i2];
    if (key >= pivot) {
      int w = (int)(key >> HSH) - P;
      if (w < 0) w = 0; if (w > WIN-1) w = WIN-1;
      int slot = (int)base[w] + (int)atomicAdd(&cntw[w], 1u);
      if (slot < LDSN) {
        int a = i2 / NPOS, pos = i2 - a * NPOS;
        u32 iref = (u32)(pos * NA + a);          // reference flat order
        sl[slot] = ((u64)key << 32) | (u64)(0xFFFFFFFFu - iref);
      }
    }
  }
  __syncthreads();

  // ---------- phase C: per-bucket register bitonic (desc) ----------
  for (int w = wid; w < WIN; w += 16) {
    int cw = (int)cntw[w];
    if (cw < 2) continue;
    int bse = (int)base[w];
    if (cw <= 64) {
      // single-register wave bitonic
      u64 v0 = (lane < cw) ? sl[bse + lane] : 0ull;
      for (int k = 2; k <= 64; k <<= 1) {
        for (int j = k >> 1; j; j >>= 1) {
          u64 o = __shfl_xor(v0, j);
          bool dir   = ((lane & k) == 0);
          bool lower = ((lane & j) == 0);
          v0 = ((v0 > o) == (lower == dir)) ? v0 : o;
        }
      }
      if (lane < cw) sl[bse + lane] = v0;
    } else {
      if (cw > 256) cw = 256;                    // impossible-case clamp
      u64 v[4];
#pragma unroll
      for (int s = 0; s < 4; ++s) {
        int idx = s*64 + lane;
        v[s] = (idx < cw) ? sl[bse + idx] : 0ull;
      }
      for (int k = 2; k <= 256; k <<= 1) {
        for (int j = k >> 1; j; j >>= 1) {
          if (j >= 64) {
            int js = j >> 6;                      // 1 or 2
#pragma unroll
            for (int sa = 0; sa < 4; ++sa) {
              int sb = sa ^ js;
              if (sb > sa) {
                int idx = sa*64 + lane;
                bool dir = ((idx & k) == 0);
                u64 A = v[sa], B = v[sb];
                if ((A < B) == dir) { v[sa] = B; v[sb] = A; }
              }
            }
          } else {
#pragma unroll
            for (int s = 0; s < 4; ++s) {
              u64 o = __shfl_xor(v[s], j);
              int idx = s*64 + lane;
              bool dir   = ((idx & k) == 0);
              bool lower = ((lane & j) == 0);
              v[s] = ((v[s] > o) == (lower == dir)) ? v[s] : o;
            }
          }
        }
      }
#pragma unroll
      for (int s = 0; s < 4; ++s) {
        int idx = s*64 + lane;
        if (idx < cw) sl[bse + idx] = v[s];
      }
    }
  }
  __syncthreads();

  // ---------- phase C2: dedicated box-gather to g_sbox (high MLP) ----------
  for (int r = tid; r < Kb; r += NTHR) {
    u32 iref = 0xFFFFFFFFu - (u32)(sl[r] & 0xFFFFFFFFull);
    int pos = iref / NA, a = iref - pos * NA;
    g_sbox[b][r] = g_boxes[b][a * NPOS + pos];
  }
  __syncthreads();   // sl/base/cntw dead; r2 free for NMS

  // ---------- phase D: 16-wave batched greedy NMS (round-6 proven) ----------
  {
    float4* kbox = (float4*)r2;                          // [2048] 32KB
    float*  kar  = (float*)(r2 + 32768);                 // [2048]
    float4* cbox = (float4*)(r2 + 40960);                // [64]
    float*  car  = (float*)(r2 + 41984);                 // [64]
    u64 (*conf16)[64] = (u64 (*)[64])(r2 + 42240);       // [16][64]
    u64* sup16 = (u64*)(r2 + 50432);                     // [16]

    // stage chunk 0 (contiguous)
    if (wid == 15) {
      float4 bx0 = (lane < Kb) ? g_sbox[b][lane] : make_float4(0.f,0.f,-1.f,-1.f);
      cbox[lane] = bx0;
      car[lane]  = (bx0.z - bx0.x + 1.0f) * (bx0.w - bx0.y + 1.0f);
    }
    __syncthreads();

    int nk = 0;
    u64 laneBitsBelow = (lane == 0) ? 0ull : (~0ull >> (64 - lane));

    for (int bs = 0; bs < Kb; bs += 64) {
      float4 bx  = cbox[lane];
      float area = car[lane];
      bool active = (bs + lane < Kb);

      // wave15: prefetch next chunk (contiguous; hidden under supp loop)
      float4 nxt = make_float4(0.f, 0.f, -1.f, -1.f);
      if (wid == 15) {
        int c2 = bs + 64 + lane;
        if (c2 < Kb) nxt = g_sbox[b][c2];
      }

      // suppression vs kept boxes: stride-16, unrolled x4
      int supp = active ? 0 : 1;
      {
        int t = wid;
        for (; t + 48 < nk; t += 64) {
          supp |= (int)iou_gt(bx, area, kbox[t],    kar[t]);
          supp |= (int)iou_gt(bx, area, kbox[t+16], kar[t+16]);
          supp |= (int)iou_gt(bx, area, kbox[t+32], kar[t+32]);
          supp |= (int)iou_gt(bx, area, kbox[t+48], kar[t+48]);
        }
        for (; t < nk; t += 16) supp |= (int)iou_gt(bx, area, kbox[t], kar[t]);
      }
      u64 sb = __ballot(supp);
      if (lane == 0) sup16[wid] = sb;

      // intra-chunk conflict bits: wave w covers j in [w*4, w*4+4)
      {
        u64 confp = 0ull;
#pragma unroll
        for (int q = 0; q < 4; ++q) {
          int j = (wid << 2) + q;
          if (iou_gt(bx, area, cbox[j], car[j])) confp |= (1ull << j);
        }
        conf16[wid][lane] = confp;
      }
      __syncthreads();   // sup16/conf16 ready; cbox free to overwrite

      if (wid == 0) {
        u64 conf = 0ull;
#pragma unroll
        for (int w = 0; w < 16; ++w) conf |= conf16[w][lane];
        conf &= laneBitsBelow;
        u64 supAll = 0ull;
#pragma unroll
        for (int w = 0; w < 16; ++w) supAll |= sup16[w];
        u64 pending = ~supAll;
        u64 keptmask = 0ull;
        while (pending) {
          int i = __ffsll(pending) - 1;
          keptmask |= (1ull << i);
          u64 confb = __ballot((int)((conf >> i) & 1ull));
          pending &= ~confb;
          pending &= ~(1ull << i);
        }
        int myPos = nk + __popcll(keptmask & laneBitsBelow);
        if (((keptmask >> lane) & 1ull) && myPos < post) {
          kbox[myPos] = bx;
          kar [myPos] = area;
          float* o = out + ((size_t)b * post + myPos) * 5;
          o[0] = (float)b; o[1] = bx.x; o[2] = bx.y; o[3] = bx.z; o[4] = bx.w;
        }
        if (lane == 0) s_nk = nk + __popcll(keptmask);
      } else if (wid == 15) {
        cbox[lane] = nxt;
        car[lane]  = (nxt.z - nxt.x + 1.0f) * (nxt.w - nxt.y + 1.0f);
      }
      __syncthreads();   // s_nk, kbox, new cbox ready
      nk = s_nk;
      if (nk >= post) break;
    }

    nk = min(nk, post);
    for (int rr = nk + tid; rr < post; rr += NTHR) {
      float* o = out + ((size_t)b * post + rr) * 5;
      o[0] = (float)b; o[1] = 0.0f; o[2] = 0.0f; o[3] = 0.0f; o[4] = 0.0f;
    }
  }

  // ---------- phase E: reset histogram for next call ----------
  {
    uint4* hz = (uint4*)&g_h15[b][0];
    uint4 z = make_uint4(0u,0u,0u,0u);
    for (int q = tid; q < HSZ/4; q += NTHR) hz[q] = z;
  }
}

extern "C" void kernel_launch(void* const* d_in, const int* in_sizes, int n_in,
                              void* d_out, int out_size, void* d_ws, size_t ws_size,
                              hipStream_t stream) {
  (void)in_sizes; (void)n_in; (void)d_ws; (void)ws_size;
  const float* cls   = (const float*)d_in[0];
  const float* dlt   = (const float*)d_in[1];
  const float* ish   = (const float*)d_in[2];
  const int*   train = (const int*)d_in[3];
  float* out = (float*)d_out;

  int post = out_size / (NB * 5);  // 300 for TEST, 2000 for TRAIN

  // allow >64KB dynamic LDS (gfx950: 160KB/CU); host-side, capture-safe
  (void)hipFuncSetAttribute((const void*)kB_sortnms,
      hipFuncAttributeMaxDynamicSharedMemorySize, DYN_LDS);

  kA_decode<<<NB*NA*(NPOS/256), 256, 0, stream>>>(cls, dlt, ish);
  kB_sortnms<<<NB, NTHR, DYN_LDS, stream>>>(out, train, post);
}

// Round 15
// 190.470 us; speedup vs baseline: 1.3079x; 1.0120x over previous
//
#include <hip/hip_runtime.h>

// ProposalLayer for Faster R-CNN RPN on MI355X — 3 kernels (attribution round).
// B=4, H=64, W=96, A=9 anchors, N=55296/image. TEST: pre=6000, post=300.
//
// kA_decode (864x256, full chip): decode boxes+keys + global 15-bit histogram.
// kB1_sort (4x1024): wave-scan pivot (~7 barriers, round-14 fix) ->
//   counting-scatter into packed bucket segments (LDS) -> per-bucket register
//   bitonic -> dedicated box-gather to g_sbox -> hist reset. Writes g_kb[b].
// kC_nms (4x1024): 16-wave batched greedy NMS (round-6 proven) from g_sbox.
// Cross-call invariants: g_h15 zeroed by kB1 at end (first call sees .bss 0).

#define NB 4
#define AH 64
#define AW 96
#define NA 9
#define NPOS (AH*AW)        // 6144
#define NPC (NPOS*NA)       // 55296
#define LDSN 8192           // candidate capacity (u64) = 64KB
#define HBITS 15
#define HSZ (1<<HBITS)      // 32768
#define HSH (32-HBITS)      // 17
#define NTHR 1024
#define WIN 2048            // bucket window
#define DYN_B1 (65536 + WIN*4*2)   // sl + base + cntw = 81920

typedef unsigned long long u64;
typedef unsigned int u32;

// anchors from _generate_anchors(16,(0.5,1,2),(8,16,32)) — verified vs numpy
__constant__ float c_anchors[NA][4] = {
  { -84.f,  -40.f,  99.f,  55.f},
  {-176.f,  -88.f, 191.f, 103.f},
  {-360.f, -184.f, 375.f, 199.f},
  { -56.f,  -56.f,  71.f,  71.f},
  {-120.f, -120.f, 135.f, 135.f},
  {-248.f, -248.f, 263.f, 263.f},
  { -36.f,  -80.f,  51.f,  95.f},
  { -80.f, -168.f,  95.f, 183.f},
  {-168.f, -344.f, 183.f, 359.f},
};

__device__ u32    g_keys[NB][NPC];   // storage order i2 = a*NPOS+pos
__device__ float4 g_boxes[NB][NPC];
__device__ u32    g_h15[NB][HSZ];
__device__ float4 g_sbox[NB][LDSN];  // boxes in exact sorted order
__device__ int    g_kb[NB];          // candidate count for kC

// exact-equivalent "iou > 0.7f": margin-guarded multiply compare with exact
// IEEE-division fallback on the ~never-taken borderline.
__device__ __forceinline__ bool iou_gt(float4 a, float areaA, float4 q, float areaQ) {
#pragma clang fp contract(off)
  float iw = fminf(a.z, q.z) - fmaxf(a.x, q.x) + 1.0f; iw = fmaxf(iw, 0.0f);
  float ih = fminf(a.w, q.w) - fmaxf(a.y, q.y) + 1.0f; ih = fmaxf(ih, 0.0f);
  float inter = iw * ih;
  float denom = areaA + areaQ - inter;
  float d = inter - 0.7f * denom;
  if (__builtin_expect(fabsf(d) <= 4e-6f * denom, 0))
    return (inter / denom) > 0.7f;
  return d > 0.0f;
}

// ================= kA: decode (full chip) =================
__global__ void __launch_bounds__(256)
kA_decode(const float* __restrict__ cls, const float* __restrict__ dlt,
          const float* __restrict__ ish) {
#pragma clang fp contract(off)
  const int UPB = NPOS/256;                  // 24
  int bid = blockIdx.x;
  int b   = bid / (NA*UPB);
  int r   = bid % (NA*UPB);
  int a   = r / UPB;
  int pos = (r % UPB) * 256 + threadIdx.x;
  int i2  = a * NPOS + pos;

  int wx = pos % AW;
  int hy = pos / AW;

  float score = cls[(b * (2*NA) + NA + a) * NPOS + pos];
  const float* dp = dlt + (b * (4*NA) + a*4) * NPOS + pos;
  float d0 = dp[0];
  float d1 = dp[NPOS];
  float d2 = dp[2*NPOS];
  float d3 = dp[3*NPOS];

  float shx = (float)(wx * 16);
  float shy = (float)(hy * 16);
  float ax1 = c_anchors[a][0] + shx;
  float ay1 = c_anchors[a][1] + shy;
  float ax2 = c_anchors[a][2] + shx;
  float ay2 = c_anchors[a][3] + shy;

  float aw_ = ax2 - ax1 + 1.0f;
  float ah_ = ay2 - ay1 + 1.0f;
  float acx = ax1 + 0.5f * aw_;
  float acy = ay1 + 0.5f * ah_;

  float pcx = d0 * aw_ + acx;
  float pcy = d1 * ah_ + acy;
  float pw  = expf(d2) * aw_;
  float ph  = expf(d3) * ah_;

  float x1 = pcx - 0.5f * pw;
  float y1 = pcy - 0.5f * ph;
  float x2 = pcx + 0.5f * pw;
  float y2 = pcy + 0.5f * ph;

  float imh = ish[b*2 + 0];
  float imw = ish[b*2 + 1];
  x1 = fminf(fmaxf(x1, 0.0f), imw - 1.0f);
  x2 = fminf(fmaxf(x2, 0.0f), imw - 1.0f);
  y1 = fminf(fmaxf(y1, 0.0f), imh - 1.0f);
  y2 = fminf(fmaxf(y2, 0.0f), imh - 1.0f);

  bool valid = ((x2 - x1 + 1.0f) >= 16.0f) && ((y2 - y1 + 1.0f) >= 16.0f);

  g_boxes[b][i2] = make_float4(x1, y1, x2, y2);

  u32 key = 0u;
  if (valid) {
    u32 ub = __float_as_uint(score);
    key = (ub >> 31) ? ~ub : (ub | 0x80000000u);  // monotonic flip
  }
  g_keys[b][i2] = key;
  atomicAdd(&g_h15[b][key >> HSH], 1u);           // key==0 -> bucket 0
}

// ================= kB1: wave-scan pivot + counting-sort + gather ============
__global__ void __launch_bounds__(NTHR)
kB1_sort(const int* __restrict__ train) {
  const int tid = threadIdx.x;
  const int b   = blockIdx.x;
  const int pre = train[0] ? 12000 : 6000;
  const int lane = tid & 63;
  const int wid  = tid >> 6;   // 16 waves

  extern __shared__ __align__(16) unsigned char smem[];
  u64* sl   = (u64*)smem;                             // [LDSN] 64KB
  u32* base = (u32*)(smem + 65536);                   // [WIN]
  u32* cntw = base + WIN;                             // [WIN]

  __shared__ u32 gsum[32];
  __shared__ u32 gsuf[33];
  __shared__ u32 wtot[16];
  __shared__ int sG;
  __shared__ int sT;
  __shared__ u32 sSP;

  if (tid == 0) { sG = -1; sT = -1; sSP = 0u; }

  // ---- A1: group sums (32 groups x 1024 bins), coalesced + shfl reduce ----
  {
    int g = tid >> 5, j = tid & 31;
    const u32* __restrict__ hg = &g_h15[b][g * 1024];
    u32 part = 0;
#pragma unroll
    for (int k = 0; k < 32; ++k) part += hg[k*32 + j];
#pragma unroll
    for (int m = 16; m >= 1; m >>= 1) part += __shfl_xor(part, m);
    if (j == 0) gsum[g] = part;
  }
  __syncthreads();                               // B1

  // ---- A2: group inclusive suffix (one wave, shfl) ----
  if (tid < 32) {
    u32 v = gsum[tid];
#pragma unroll
    for (int m = 1; m < 32; m <<= 1) {
      u32 t = __shfl_down(v, m);
      if (tid + m < 32) v += t;
    }
    gsuf[tid] = v;
    if (tid == 0) gsuf[32] = 0u;
  }
  __syncthreads();                               // B2

  // ---- A3: pivot group G (unique boundary writer) ----
  if (tid < 32 && gsuf[tid] >= (u32)pre &&
      (tid == 31 || gsuf[tid+1] < (u32)pre)) sG = tid;
  __syncthreads();                               // B3

  const int G  = sG;
  const int Gc = (G < 0) ? 0 : G;

  // ---- A4: within-group suffix (wave shfl + 16-entry combine) ----
  u32 hv = g_h15[b][Gc*1024 + (wid<<6) + lane];
  u32 sfx = hv;
#pragma unroll
  for (int m = 1; m < 64; m <<= 1) {
    u32 t = __shfl_down(sfx, m);
    if (lane + m < 64) sfx += t;
  }
  if (lane == 0) wtot[wid] = sfx;
  __syncthreads();                               // B4
  {
    u32 wsuf = 0;
    for (int w2 = wid + 1; w2 < 16; ++w2) wsuf += wtot[w2];
    u32 sfxg = __shfl(sfx, 0) - ( __shfl(sfx,0) - sfx );  // == sfx (keep simple)
    sfxg = sfx + wsuf;                            // inclusive suffix in group
    if (G >= 0) {
      int t = (wid<<6) + lane;
      u32 S = gsuf[G+1] + sfxg;
      bool c0 = (S >= (u32)pre);
      bool c1 = (t < 1023) && ((S - hv) >= (u32)pre);
      if (c0 && !c1) {
        int bin = Gc*1024 + t;
        if (bin >= 1) { sT = t; sSP = S; }       // unique boundary writer
      }
    }
  }
  __syncthreads();                               // B5

  int P; u32 SP;
  if (sT >= 0) { P = Gc*1024 + sT; SP = sSP; }
  else         { P = 1; SP = gsuf[0] - g_h15[b][0]; }  // degenerate: all valid
  const u32 pivot = (u32)P << HSH;

  // ---- A6: window prefix (2048 bins from P) -> bases; zero cntw ----
  {
    int b0 = P + (wid<<7) + (lane<<1);
    u32 h0 = (b0 < HSZ) ? g_h15[b][b0] : 0u;
    u32 h1 = (b0+1 < HSZ) ? g_h15[b][b0+1] : 0u;
    u32 pfx = h0 + h1;
#pragma unroll
    for (int m = 1; m < 64; m <<= 1) {
      u32 t = __shfl_up(pfx, m);
      if (lane >= m) pfx += t;
    }
    if (lane == 63) wtot[wid] = pfx;
    __syncthreads();                             // B6
    u32 woff = 0;
    for (int w2 = 0; w2 < wid; ++w2) woff += wtot[w2];
    u32 pc1 = woff + pfx;                        // inclusive through bin b0+1
    u32 pc0 = pc1 - h1;                          // inclusive through bin b0
    int w0 = (wid<<7) + (lane<<1);
    base[w0]   = SP - pc0;                       // count of keys in bins > P+w
    base[w0+1] = SP - pc1;
    cntw[w0] = 0u; cntw[w0+1] = 0u;
  }
  __syncthreads();                               // B7

  int C = (int)SP; if (C > LDSN) C = LDSN;
  const int Kb = min(pre, C);
  if (tid == 0) g_kb[b] = Kb;

  // ---------- phase B: counting-scatter into packed bucket segments ----------
  for (int i2 = tid; i2 < NPC; i2 += NTHR) {
    u32 key = g_keys[b][i2];
    if (key >= pivot) {
      int w = (int)(key >> HSH) - P;
      if (w < 0) w = 0; if (w > WIN-1) w = WIN-1;
      int slot = (int)base[w] + (int)atomicAdd(&cntw[w], 1u);
      if (slot < LDSN) {
        int a = i2 / NPOS, pos = i2 - a * NPOS;
        u32 iref = (u32)(pos * NA + a);          // reference flat order
        sl[slot] = ((u64)key << 32) | (u64)(0xFFFFFFFFu - iref);
      }
    }
  }
  __syncthreads();

  // ---------- phase C: per-bucket register bitonic (desc) ----------
  for (int w = wid; w < WIN; w += 16) {
    int cw = (int)cntw[w];
    if (cw < 2) continue;
    int bse = (int)base[w];
    if (cw <= 64) {
      u64 v0 = (lane < cw) ? sl[bse + lane] : 0ull;
      for (int k = 2; k <= 64; k <<= 1) {
        for (int j = k >> 1; j; j >>= 1) {
          u64 o = __shfl_xor(v0, j);
          bool dir   = ((lane & k) == 0);
          bool lower = ((lane & j) == 0);
          v0 = ((v0 > o) == (lower == dir)) ? v0 : o;
        }
      }
      if (lane < cw) sl[bse + lane] = v0;
    } else {
      if (cw > 256) cw = 256;                    // impossible-case clamp
      u64 v[4];
#pragma unroll
      for (int s = 0; s < 4; ++s) {
        int idx = s*64 + lane;
        v[s] = (idx < cw) ? sl[bse + idx] : 0ull;
      }
      for (int k = 2; k <= 256; k <<= 1) {
        for (int j = k >> 1; j; j >>= 1) {
          if (j >= 64) {
            int js = j >> 6;
#pragma unroll
            for (int sa = 0; sa < 4; ++sa) {
              int sb = sa ^ js;
              if (sb > sa) {
                int idx = sa*64 + lane;
                bool dir = ((idx & k) == 0);
                u64 A = v[sa], B = v[sb];
                if ((A < B) == dir) { v[sa] = B; v[sb] = A; }
              }
            }
          } else {
#pragma unroll
            for (int s = 0; s < 4; ++s) {
              u64 o = __shfl_xor(v[s], j);
              int idx = s*64 + lane;
              bool dir   = ((idx & k) == 0);
              bool lower = ((lane & j) == 0);
              v[s] = ((v[s] > o) == (lower == dir)) ? v[s] : o;
            }
          }
        }
      }
#pragma unroll
      for (int s = 0; s < 4; ++s) {
        int idx = s*64 + lane;
        if (idx < cw) sl[bse + idx] = v[s];
      }
    }
  }
  __syncthreads();

  // ---------- phase C2: dedicated box-gather to g_sbox (high MLP) ----------
  for (int r = tid; r < Kb; r += NTHR) {
    u32 iref = 0xFFFFFFFFu - (u32)(sl[r] & 0xFFFFFFFFull);
    int pos = iref / NA, a = iref - pos * NA;
    g_sbox[b][r] = g_boxes[b][a * NPOS + pos];
  }

  // ---------- phase E: reset histogram for next call (all reads done) -------
  {
    uint4* hz = (uint4*)&g_h15[b][0];
    uint4 z = make_uint4(0u,0u,0u,0u);
    for (int q = tid; q < HSZ/4; q += NTHR) hz[q] = z;
  }
}

// ================= kC: 16-wave batched greedy NMS (round-6 proven) ==========
__global__ void __launch_bounds__(NTHR)
kC_nms(float* __restrict__ out, int post) {
#pragma clang fp contract(off)
  const int tid = threadIdx.x;
  const int b   = blockIdx.x;
  const int lane = tid & 63;
  const int wid  = tid >> 6;   // 16 waves

  __shared__ float4 kbox[2048];
  __shared__ float  kar [2048];
  __shared__ float4 cbox[64];
  __shared__ float  car [64];
  __shared__ u64 conf16[16][64];
  __shared__ u64 sup16[16];
  __shared__ int s_nk;

  const int Kb = g_kb[b];
  if (tid == 0) s_nk = 0;

  // stage chunk 0 (contiguous)
  if (wid == 15) {
    float4 bx0 = (lane < Kb) ? g_sbox[b][lane] : make_float4(0.f,0.f,-1.f,-1.f);
    cbox[lane] = bx0;
    car[lane]  = (bx0.z - bx0.x + 1.0f) * (bx0.w - bx0.y + 1.0f);
  }
  __syncthreads();

  int nk = 0;
  u64 laneBitsBelow = (lane == 0) ? 0ull : (~0ull >> (64 - lane));

  for (int bs = 0; bs < Kb; bs += 64) {
    float4 bx  = cbox[lane];
    float area = car[lane];
    bool active = (bs + lane < Kb);

    // wave15: prefetch next chunk (contiguous; hidden under supp loop)
    float4 nxt = make_float4(0.f, 0.f, -1.f, -1.f);
    if (wid == 15) {
      int c2 = bs + 64 + lane;
      if (c2 < Kb) nxt = g_sbox[b][c2];
    }

    // suppression vs kept boxes: stride-16, unrolled x4
    int supp = active ? 0 : 1;
    {
      int t = wid;
      for (; t + 48 < nk; t += 64) {
        supp |= (int)iou_gt(bx, area, kbox[t],    kar[t]);
        supp |= (int)iou_gt(bx, area, kbox[t+16], kar[t+16]);
        supp |= (int)iou_gt(bx, area, kbox[t+32], kar[t+32]);
        supp |= (int)iou_gt(bx, area, kbox[t+48], kar[t+48]);
      }
      for (; t < nk; t += 16) supp |= (int)iou_gt(bx, area, kbox[t], kar[t]);
    }
    u64 sb = __ballot(supp);
    if (lane == 0) sup16[wid] = sb;

    // intra-chunk conflict bits: wave w covers j in [w*4, w*4+4)
    {
      u64 confp = 0ull;
#pragma unroll
      for (int q = 0; q < 4; ++q) {
        int j = (wid << 2) + q;
        if (iou_gt(bx, area, cbox[j], car[j])) confp |= (1ull << j);
      }
      conf16[wid][lane] = confp;
    }
    __syncthreads();   // sup16/conf16 ready; cbox free to overwrite

    if (wid == 0) {
      u64 conf = 0ull;
#pragma unroll
      for (int w = 0; w < 16; ++w) conf |= conf16[w][lane];
      conf &= laneBitsBelow;
      u64 supAll = 0ull;
#pragma unroll
      for (int w = 0; w < 16; ++w) supAll |= sup16[w];
      u64 pending = ~supAll;
      u64 keptmask = 0ull;
      while (pending) {
        int i = __ffsll(pending) - 1;
        keptmask |= (1ull << i);
        u64 confb = __ballot((int)((conf >> i) & 1ull));
        pending &= ~confb;
        pending &= ~(1ull << i);
      }
      int myPos = nk + __popcll(keptmask & laneBitsBelow);
      if (((keptmask >> lane) & 1ull) && myPos < post) {
        kbox[myPos] = bx;
        kar [myPos] = area;
        float* o = out + ((size_t)b * post + myPos) * 5;
        o[0] = (float)b; o[1] = bx.x; o[2] = bx.y; o[3] = bx.z; o[4] = bx.w;
      }
      if (lane == 0) s_nk = nk + __popcll(keptmask);
    } else if (wid == 15) {
      cbox[lane] = nxt;
      car[lane]  = (nxt.z - nxt.x + 1.0f) * (nxt.w - nxt.y + 1.0f);
    }
    __syncthreads();   // s_nk, kbox, new cbox ready
    nk = s_nk;
    if (nk >= post) break;
  }

  nk = min(nk, post);
  for (int rr = nk + tid; rr < post; rr += NTHR) {
    float* o = out + ((size_t)b * post + rr) * 5;
    o[0] = (float)b; o[1] = 0.0f; o[2] = 0.0f; o[3] = 0.0f; o[4] = 0.0f;
  }
}

extern "C" void kernel_launch(void* const* d_in, const int* in_sizes, int n_in,
                              void* d_out, int out_size, void* d_ws, size_t ws_size,
                              hipStream_t stream) {
  (void)in_sizes; (void)n_in; (void)d_ws; (void)ws_size;
  const float* cls   = (const float*)d_in[0];
  const float* dlt   = (const float*)d_in[1];
  const float* ish   = (const float*)d_in[2];
  const int*   train = (const int*)d_in[3];
  float* out = (float*)d_out;

  int post = out_size / (NB * 5);  // 300 for TEST, 2000 for TRAIN

  // allow >64KB dynamic LDS for kB1 (gfx950: 160KB/CU); host-side, capture-safe
  (void)hipFuncSetAttribute((const void*)kB1_sort,
      hipFuncAttributeMaxDynamicSharedMemorySize, DYN_B1);

  kA_decode<<<NB*NA*(NPOS/256), 256, 0, stream>>>(cls, dlt, ish);
  kB1_sort<<<NB, NTHR, DYN_B1, stream>>>(train);
  kC_nms<<<NB, NTHR, 0, stream>>>(out, post);
}